// Round 2
// baseline (221.226 us; speedup 1.0000x reference)
//
#include <hip/hip_runtime.h>
#include <hip/hip_bf16.h>

// Fused MHA forward (B=8, I=J=1024, WIDTH=512, NH=8, HD=64), fp32 in/out.
// R2: single-pass attention (register-held bf16 P, deferred normalization),
// 2-phase double-buffered staging everywhere, merged QKV projection GEMM.

typedef __hip_bfloat16 bf16;
typedef __attribute__((ext_vector_type(8))) short bf16x8;   // MFMA A/B frag (4 VGPR)
typedef __attribute__((ext_vector_type(4))) float f32x4;    // MFMA C/D frag

#define BATCH 8
#define SEQ   1024
#define WIDTH 512
#define NHEAD 8
#define HD    64
#define SCALE_F 0.044194173824159216f     // 512^-0.5 (width, per reference!)

static __device__ __forceinline__ unsigned short f2bf(float x) {
  union { float f; unsigned u; } a; a.f = x;
  unsigned r = a.u + 0x7fffu + ((a.u >> 16) & 1u);   // RNE
  return (unsigned short)(r >> 16);
}
static __device__ __forceinline__ float bf2f(unsigned short u) {
  union { unsigned u; float f; } a; a.u = ((unsigned)u) << 16; return a.f;
}

static __device__ __forceinline__ void gload_lds16(const void* g, void* l) {
  __builtin_amdgcn_global_load_lds((const __attribute__((address_space(1))) void*)g,
                                   (__attribute__((address_space(3))) void*)l,
                                   16, 0, 0);
}

// Swizzled LDS tile: rows of 64 bf16 (128B); 16B-unit phys col = logical ^ (row&7).
// Staging pre-applies the inverse on the GLOBAL source; reads apply it here.
static __device__ __forceinline__ bf16x8 frag_ld(const short* tile, int row, int c16) {
  int p = c16 ^ (row & 7);
  return *(const bf16x8*)(tile + row*64 + p*8);
}

// ---------------- cast fp32 -> bf16 (q,k,v + 4 weights) ----------------
__global__ void cast_all_kernel(const float* __restrict__ q, const float* __restrict__ k,
                                const float* __restrict__ v, const float* __restrict__ wq,
                                const float* __restrict__ wk, const float* __restrict__ wv,
                                const float* __restrict__ wo, bf16* __restrict__ wsb) {
  const long NQ = 1048576;   // float4 groups per q/k/v (8192*512/4)
  const long NW = 65536;     // per weight (512*512/4)
  long g = (long)blockIdx.x * blockDim.x + threadIdx.x;
  const float* src; bf16* dst; long o;
  if (g < 3*NQ) {
    int t = (int)(g / NQ); o = g - (long)t*NQ;
    src = (t==0) ? q : ((t==1) ? k : v);
    dst = wsb + (size_t)t * 4194304;
  } else {
    long g2 = g - 3*NQ;
    if (g2 >= 4*NW) return;
    int t = (int)(g2 / NW); o = g2 - (long)t*NW;
    src = (t==0) ? wq : ((t==1) ? wk : ((t==2) ? wv : wo));
    dst = wsb + (size_t)3*4194304 + (size_t)t * 262144;
  }
  float4 f = ((const float4*)src)[o];
  ushort4 r4;
  r4.x = f2bf(f.x); r4.y = f2bf(f.y); r4.z = f2bf(f.z); r4.w = f2bf(f.w);
  ((ushort4*)dst)[o] = r4;
}

// ---------------- GEMM: C[8192][512] = A[8192][512] @ W[512][512]^T ----------------
// 128x128 tile, BK=64, 4 waves (2x2), 2-phase double-buffered staging.
// NZ=3: blockIdx.z selects (A,W,C) triple (merged QKV). NZ=1: single GEMM.
template<int F32OUT, int NZ>
__global__ __launch_bounds__(256) void gemm_bt(const bf16* __restrict__ A0, const bf16* __restrict__ A1,
                                               const bf16* __restrict__ A2, const bf16* __restrict__ W0,
                                               const bf16* __restrict__ W1, const bf16* __restrict__ W2,
                                               void* __restrict__ C0, void* __restrict__ C1,
                                               void* __restrict__ C2) {
  __shared__ short As[2][128*64];
  __shared__ short Bs[2][128*64];
  const bf16* A; const bf16* Bw; void* Cout;
  if (NZ == 1 || blockIdx.z == 0) { A = A0; Bw = W0; Cout = C0; }
  else if (blockIdx.z == 1)       { A = A1; Bw = W1; Cout = C1; }
  else                            { A = A2; Bw = W2; Cout = C2; }

  const int lane = threadIdx.x & 63;
  const int wid  = threadIdx.x >> 6;
  const int m0 = blockIdx.x * 128;
  const int n0 = blockIdx.y * 128;
  const int wm = (wid >> 1) * 64;
  const int wn = (wid & 1) * 64;
  const int lrow = lane >> 3;
  const int swz  = ((lane & 7) ^ lrow) * 8;

  const f32x4 zero4 = {0.f,0.f,0.f,0.f};
  f32x4 acc[4][4];
  for (int i=0;i<4;++i) for (int j=0;j<4;++j) acc[i][j] = zero4;

  auto stage = [&](int buf, int t) {
    const int k0 = t * 64;
    for (int i = 0; i < 4; ++i) {
      int c = wid*4 + i;
      int row = c*8 + lrow;
      gload_lds16(A  + (size_t)(m0 + row)*WIDTH + k0 + swz, &As[buf][c*512]);
      gload_lds16(Bw + (size_t)(n0 + row)*WIDTH + k0 + swz, &Bs[buf][c*512]);
    }
  };

  stage(0, 0);
  asm volatile("s_waitcnt vmcnt(0)" ::: "memory");
  __syncthreads();
  int cur = 0;

  for (int t = 0; t < 8; ++t) {
    if (t < 7) stage(cur ^ 1, t + 1);
    for (int kc = 0; kc < 2; ++kc) {
      bf16x8 af[4], bfr[4];
      for (int mf=0; mf<4; ++mf) af[mf]  = frag_ld(&As[cur][0], wm + mf*16 + (lane&15), (lane>>4) + kc*4);
      for (int nf=0; nf<4; ++nf) bfr[nf] = frag_ld(&Bs[cur][0], wn + nf*16 + (lane&15), (lane>>4) + kc*4);
      for (int mf=0; mf<4; ++mf)
        for (int nf=0; nf<4; ++nf)
          acc[mf][nf] = __builtin_amdgcn_mfma_f32_16x16x32_bf16(af[mf], bfr[nf], acc[mf][nf], 0,0,0);
    }
    if (t < 7) {
      asm volatile("s_waitcnt vmcnt(0)" ::: "memory");
      __syncthreads();
      cur ^= 1;
    }
  }
  // epilogue: C row = (lane>>4)*4+r, col = lane&15
  for (int mf=0; mf<4; ++mf)
    for (int nf=0; nf<4; ++nf) {
      int col = n0 + wn + nf*16 + (lane & 15);
      for (int r=0; r<4; ++r) {
        int row = m0 + wm + mf*16 + (lane>>4)*4 + r;
        if (F32OUT)
          ((float*)Cout)[(size_t)row*WIDTH + col] = acc[mf][nf][r];
        else
          ((unsigned short*)Cout)[(size_t)row*WIDTH + col] = f2bf(acc[mf][nf][r]);
      }
    }
}

// ---------------- V transpose: per head (1024,64) -> (64,1024) ----------------
__global__ __launch_bounds__(256) void transpose_v(const bf16* __restrict__ Vh,
                                                   bf16* __restrict__ Vt) {
  __shared__ short t[64][72];
  int h  = blockIdx.x >> 4;
  int j0 = (blockIdx.x & 15) * 64;
  const bf16* src = Vh + (size_t)h * (SEQ*HD);
  bf16* dst = Vt + (size_t)h * (SEQ*HD);
  int tid = threadIdx.x;
  int r  = tid >> 2;
  int c0 = (tid & 3) * 16;
  bf16x8 v0 = *(const bf16x8*)(src + (size_t)(j0 + r)*HD + c0);
  bf16x8 v1 = *(const bf16x8*)(src + (size_t)(j0 + r)*HD + c0 + 8);
  for (int i = 0; i < 8; ++i) { t[r][c0+i] = v0[i]; t[r][c0+8+i] = v1[i]; }
  __syncthreads();
  bf16x8 w0, w1;
  for (int i = 0; i < 8; ++i) { w0[i] = t[c0+i][r]; w1[i] = t[c0+8+i][r]; }
  *(bf16x8*)(dst + (size_t)r*SEQ + j0 + c0)     = w0;
  *(bf16x8*)(dst + (size_t)r*SEQ + j0 + c0 + 8) = w1;
}

// ---------------- fused single-pass attention ----------------
// Block = 4 waves x 16 rows = 64 q-rows of one head. One pass over j-tiles:
// QK^T -> exp -> {register-stash bf16 P, LDS roundtrip for PV}. Normalization
// deferred: ctx *= 1/l at the end; attn_weight written once in epilogue.
__global__ __launch_bounds__(256) void attn_kernel(const bf16* __restrict__ Qh,
                                                   const bf16* __restrict__ Kh,
                                                   const bf16* __restrict__ Vt,
                                                   float* __restrict__ attn_out,
                                                   bf16* __restrict__ ctx) {
  __shared__ short Ks[2][64*64];     // [j][d] swizzled, double-buffered
  __shared__ short Vs[2][64*64];     // [d][j] swizzled (from Vt)
  __shared__ short Ws[4][16*64];     // per-wave P tile [i][j] swizzled

  const int lane = threadIdx.x & 63;
  const int wid  = threadIdx.x >> 6;
  const int h  = blockIdx.x >> 4;            // b*8+n
  const int i0 = (blockIdx.x & 15) * 64;
  const int b  = h >> 3;
  const int nh = h & 7;

  const bf16* Qhead  = Qh + (size_t)h * (SEQ*HD);
  const bf16* Khead  = Kh + (size_t)h * (SEQ*HD);
  const bf16* Vthead = Vt + (size_t)h * (SEQ*HD);

  const int lrow = lane >> 3;
  const int swz  = ((lane & 7) ^ lrow) * 8;

  const int qrow = i0 + wid*16 + (lane & 15);
  bf16x8 qf[2];
  qf[0] = *(const bf16x8*)(Qhead + (size_t)qrow*HD + (lane>>4)*8);
  qf[1] = *(const bf16x8*)(Qhead + (size_t)qrow*HD + 32 + (lane>>4)*8);

  const f32x4 zero4 = {0.f,0.f,0.f,0.f};
  float lsum[4] = {0.f,0.f,0.f,0.f};
  f32x4 cacc[4] = {zero4, zero4, zero4, zero4};
  unsigned Pst[16][8];               // bf16-pair stash of exp(S); static indices only!
  short* Wsw = &Ws[wid][0];

  auto stageKV = [&](int buf, int jt) {
    const int j0 = jt * 64;
    for (int i = 0; i < 2; ++i) {
      int c = wid*2 + i;
      gload_lds16(Khead  + (size_t)(j0 + c*8 + lrow)*HD + swz,  &Ks[buf][c*512]);
      gload_lds16(Vthead + (size_t)(c*8 + lrow)*SEQ + j0 + swz, &Vs[buf][c*512]);
    }
  };

  stageKV(0, 0);
  asm volatile("s_waitcnt vmcnt(0)" ::: "memory");
  __syncthreads();
  int cur = 0;

  #pragma unroll
  for (int jt = 0; jt < 16; ++jt) {
    if (jt < 15) stageKV(cur ^ 1, jt + 1);
    // QK^T
    f32x4 sac[4] = {zero4, zero4, zero4, zero4};
    #pragma unroll
    for (int kc = 0; kc < 2; ++kc)
      #pragma unroll
      for (int jf = 0; jf < 4; ++jf) {
        bf16x8 kf = frag_ld(&Ks[cur][0], jf*16 + (lane & 15), (lane>>4) + kc*4);
        sac[jf] = __builtin_amdgcn_mfma_f32_16x16x32_bf16(qf[kc], kf, sac[jf], 0, 0, 0);
      }
    // exp, accumulate denominator, stash bf16 P (regs) + LDS for PV
    #pragma unroll
    for (int jf = 0; jf < 4; ++jf) {
      unsigned short bb[4];
      #pragma unroll
      for (int r = 0; r < 4; ++r) {
        float w = __expf(sac[jf][r] * SCALE_F);
        lsum[r] += w;
        bb[r] = f2bf(w);
        int row = (lane>>4)*4 + r;
        int col = jf*16 + (lane & 15);
        Wsw[row*64 + (((col>>3) ^ (row & 7))<<3) + (col & 7)] = (short)bb[r];
      }
      Pst[jt][jf*2+0] = (unsigned)bb[0] | ((unsigned)bb[1] << 16);
      Pst[jt][jf*2+1] = (unsigned)bb[2] | ((unsigned)bb[3] << 16);
    }
    asm volatile("s_waitcnt lgkmcnt(0)" ::: "memory");  // same-wave Ws visibility
    // PV with unnormalized P
    #pragma unroll
    for (int kc = 0; kc < 2; ++kc) {
      bf16x8 wa = frag_ld(Wsw, lane & 15, (lane>>4) + kc*4);
      #pragma unroll
      for (int df = 0; df < 4; ++df) {
        bf16x8 vb = frag_ld(&Vs[cur][0], df*16 + (lane & 15), (lane>>4) + kc*4);
        cacc[df] = __builtin_amdgcn_mfma_f32_16x16x32_bf16(wa, vb, cacc[df], 0, 0, 0);
      }
    }
    if (jt < 15) {
      asm volatile("s_waitcnt vmcnt(0)" ::: "memory");
      __syncthreads();
      cur ^= 1;
    }
  }

  // denominator: reduce across the 16 lanes holding different j-cols
  #pragma unroll
  for (int m = 1; m < 16; m <<= 1)
    #pragma unroll
    for (int r = 0; r < 4; ++r)
      lsum[r] += __shfl_xor(lsum[r], m, 64);
  float linv[4];
  #pragma unroll
  for (int r = 0; r < 4; ++r) linv[r] = 1.0f / lsum[r];

  // ctx[b][i'][nh*64+d] with deferred normalization
  #pragma unroll
  for (int df = 0; df < 4; ++df)
    #pragma unroll
    for (int r = 0; r < 4; ++r) {
      int irow = i0 + wid*16 + (lane>>4)*4 + r;
      ((unsigned short*)ctx)[(size_t)(b*SEQ + irow)*WIDTH + nh*HD + df*16 + (lane & 15)]
          = f2bf(cacc[df][r] * linv[r]);
    }

  // attn_weight: single write of all 16 tiles from the register stash
  float* aw = attn_out + (size_t)((size_t)h*SEQ + i0 + wid*16 + (lane>>4)*4)*SEQ + (lane & 15);
  #pragma unroll
  for (int jt = 0; jt < 16; ++jt)
    #pragma unroll
    for (int jf = 0; jf < 4; ++jf) {
      unsigned p0 = Pst[jt][jf*2+0], p1 = Pst[jt][jf*2+1];
      int c = jt*64 + jf*16;
      aw[(size_t)0*SEQ + c] = bf2f((unsigned short)(p0 & 0xffff)) * linv[0];
      aw[(size_t)1*SEQ + c] = bf2f((unsigned short)(p0 >> 16))    * linv[1];
      aw[(size_t)2*SEQ + c] = bf2f((unsigned short)(p1 & 0xffff)) * linv[2];
      aw[(size_t)3*SEQ + c] = bf2f((unsigned short)(p1 >> 16))    * linv[3];
    }
}

// ---------------- launcher ----------------
extern "C" void kernel_launch(void* const* d_in, const int* in_sizes, int n_in,
                              void* d_out, int out_size, void* d_ws, size_t ws_size,
                              hipStream_t stream) {
  const float* q  = (const float*)d_in[0];
  const float* k  = (const float*)d_in[1];
  const float* v  = (const float*)d_in[2];
  const float* wq = (const float*)d_in[3];
  const float* wk = (const float*)d_in[4];
  const float* wv = (const float*)d_in[5];
  const float* wo = (const float*)d_in[6];

  bf16* wsb = (bf16*)d_ws;
  bf16* qb  = wsb;
  bf16* kb  = qb + 4194304;
  bf16* vb  = kb + 4194304;
  bf16* wqb = vb + 4194304;
  bf16* wkb = wqb + 262144;
  bf16* wvb = wkb + 262144;
  bf16* wob = wvb + 262144;
  bf16* Qh  = wob + 262144;
  bf16* Kh  = Qh + 4194304;
  bf16* Vh  = Kh + 4194304;
  bf16* Vt  = Vh + 4194304;
  bf16* ctx = Vt + 4194304;

  float* x_out    = (float*)d_out;             // (8,1024,512)
  float* attn_out = (float*)d_out + 4194304;   // (8,8,1024,1024)

  cast_all_kernel<<<13312, 256, 0, stream>>>(q, k, v, wq, wk, wv, wo, wsb);
  gemm_bt<0,3><<<dim3(64,4,3), 256, 0, stream>>>(qb, kb, vb, wqb, wkb, wvb,
                                                 (void*)Qh, (void*)Kh, (void*)Vh);
  transpose_v<<<1024, 256, 0, stream>>>(Vh, Vt);
  attn_kernel<<<1024, 256, 0, stream>>>(Qh, Kh, Vt, attn_out, ctx);
  gemm_bt<1,1><<<dim3(64,4,1), 256, 0, stream>>>(ctx, nullptr, nullptr, wob, nullptr, nullptr,
                                                 (void*)x_out, nullptr, nullptr);
}

// Round 3
// 152.104 us; speedup vs baseline: 1.4544x; 1.4544x over previous
//
#include <hip/hip_runtime.h>
#include <hip/hip_bf16.h>

// Fused MHA forward (B=8, I=J=1024, WIDTH=512, NH=8, HD=64), fp32 in/out.
// R3: attention reverted to 2-pass (no register P stash -- R2's 128-VGPR stash
// spilled to scratch, 4x read amplification, 225us). Double-buffered staging
// in both passes; merged QKV GEMM kept.

typedef __hip_bfloat16 bf16;
typedef __attribute__((ext_vector_type(8))) short bf16x8;   // MFMA A/B frag (4 VGPR)
typedef __attribute__((ext_vector_type(4))) float f32x4;    // MFMA C/D frag

#define BATCH 8
#define SEQ   1024
#define WIDTH 512
#define NHEAD 8
#define HD    64
#define SCALE_F 0.044194173824159216f     // 512^-0.5 (width, per reference!)

static __device__ __forceinline__ unsigned short f2bf(float x) {
  union { float f; unsigned u; } a; a.f = x;
  unsigned r = a.u + 0x7fffu + ((a.u >> 16) & 1u);   // RNE
  return (unsigned short)(r >> 16);
}

static __device__ __forceinline__ void gload_lds16(const void* g, void* l) {
  __builtin_amdgcn_global_load_lds((const __attribute__((address_space(1))) void*)g,
                                   (__attribute__((address_space(3))) void*)l,
                                   16, 0, 0);
}

// Swizzled LDS tile: rows of 64 bf16 (128B); 16B-unit phys col = logical ^ (row&7).
// Staging pre-applies the inverse on the GLOBAL source; reads apply it here.
static __device__ __forceinline__ bf16x8 frag_ld(const short* tile, int row, int c16) {
  int p = c16 ^ (row & 7);
  return *(const bf16x8*)(tile + row*64 + p*8);
}

// ---------------- cast fp32 -> bf16 (q,k,v + 4 weights) ----------------
__global__ void cast_all_kernel(const float* __restrict__ q, const float* __restrict__ k,
                                const float* __restrict__ v, const float* __restrict__ wq,
                                const float* __restrict__ wk, const float* __restrict__ wv,
                                const float* __restrict__ wo, bf16* __restrict__ wsb) {
  const long NQ = 1048576;   // float4 groups per q/k/v (8192*512/4)
  const long NW = 65536;     // per weight (512*512/4)
  long g = (long)blockIdx.x * blockDim.x + threadIdx.x;
  const float* src; bf16* dst; long o;
  if (g < 3*NQ) {
    int t = (int)(g / NQ); o = g - (long)t*NQ;
    src = (t==0) ? q : ((t==1) ? k : v);
    dst = wsb + (size_t)t * 4194304;
  } else {
    long g2 = g - 3*NQ;
    if (g2 >= 4*NW) return;
    int t = (int)(g2 / NW); o = g2 - (long)t*NW;
    src = (t==0) ? wq : ((t==1) ? wk : ((t==2) ? wv : wo));
    dst = wsb + (size_t)3*4194304 + (size_t)t * 262144;
  }
  float4 f = ((const float4*)src)[o];
  ushort4 r4;
  r4.x = f2bf(f.x); r4.y = f2bf(f.y); r4.z = f2bf(f.z); r4.w = f2bf(f.w);
  ((ushort4*)dst)[o] = r4;
}

// ---------------- GEMM: C[8192][512] = A[8192][512] @ W[512][512]^T ----------------
// 128x128 tile, BK=64, 4 waves (2x2), 2-phase double-buffered staging.
// NZ=3: blockIdx.z selects (A,W,C) triple (merged QKV). NZ=1: single GEMM.
template<int F32OUT, int NZ>
__global__ __launch_bounds__(256) void gemm_bt(const bf16* __restrict__ A0, const bf16* __restrict__ A1,
                                               const bf16* __restrict__ A2, const bf16* __restrict__ W0,
                                               const bf16* __restrict__ W1, const bf16* __restrict__ W2,
                                               void* __restrict__ C0, void* __restrict__ C1,
                                               void* __restrict__ C2) {
  __shared__ short As[2][128*64];
  __shared__ short Bs[2][128*64];
  const bf16* A; const bf16* Bw; void* Cout;
  if (NZ == 1 || blockIdx.z == 0) { A = A0; Bw = W0; Cout = C0; }
  else if (blockIdx.z == 1)       { A = A1; Bw = W1; Cout = C1; }
  else                            { A = A2; Bw = W2; Cout = C2; }

  const int lane = threadIdx.x & 63;
  const int wid  = threadIdx.x >> 6;
  const int m0 = blockIdx.x * 128;
  const int n0 = blockIdx.y * 128;
  const int wm = (wid >> 1) * 64;
  const int wn = (wid & 1) * 64;
  const int lrow = lane >> 3;
  const int swz  = ((lane & 7) ^ lrow) * 8;

  const f32x4 zero4 = {0.f,0.f,0.f,0.f};
  f32x4 acc[4][4];
  for (int i=0;i<4;++i) for (int j=0;j<4;++j) acc[i][j] = zero4;

  auto stage = [&](int buf, int t) {
    const int k0 = t * 64;
    for (int i = 0; i < 4; ++i) {
      int c = wid*4 + i;
      int row = c*8 + lrow;
      gload_lds16(A  + (size_t)(m0 + row)*WIDTH + k0 + swz, &As[buf][c*512]);
      gload_lds16(Bw + (size_t)(n0 + row)*WIDTH + k0 + swz, &Bs[buf][c*512]);
    }
  };

  stage(0, 0);
  asm volatile("s_waitcnt vmcnt(0)" ::: "memory");
  __syncthreads();
  int cur = 0;

  for (int t = 0; t < 8; ++t) {
    if (t < 7) stage(cur ^ 1, t + 1);
    for (int kc = 0; kc < 2; ++kc) {
      bf16x8 af[4], bfr[4];
      for (int mf=0; mf<4; ++mf) af[mf]  = frag_ld(&As[cur][0], wm + mf*16 + (lane&15), (lane>>4) + kc*4);
      for (int nf=0; nf<4; ++nf) bfr[nf] = frag_ld(&Bs[cur][0], wn + nf*16 + (lane&15), (lane>>4) + kc*4);
      for (int mf=0; mf<4; ++mf)
        for (int nf=0; nf<4; ++nf)
          acc[mf][nf] = __builtin_amdgcn_mfma_f32_16x16x32_bf16(af[mf], bfr[nf], acc[mf][nf], 0,0,0);
    }
    if (t < 7) {
      asm volatile("s_waitcnt vmcnt(0)" ::: "memory");
      __syncthreads();
      cur ^= 1;
    }
  }
  // epilogue: C row = (lane>>4)*4+r, col = lane&15
  for (int mf=0; mf<4; ++mf)
    for (int nf=0; nf<4; ++nf) {
      int col = n0 + wn + nf*16 + (lane & 15);
      for (int r=0; r<4; ++r) {
        int row = m0 + wm + mf*16 + (lane>>4)*4 + r;
        if (F32OUT)
          ((float*)Cout)[(size_t)row*WIDTH + col] = acc[mf][nf][r];
        else
          ((unsigned short*)Cout)[(size_t)row*WIDTH + col] = f2bf(acc[mf][nf][r]);
      }
    }
}

// ---------------- V transpose: per head (1024,64) -> (64,1024) ----------------
__global__ __launch_bounds__(256) void transpose_v(const bf16* __restrict__ Vh,
                                                   bf16* __restrict__ Vt) {
  __shared__ short t[64][72];
  int h  = blockIdx.x >> 4;
  int j0 = (blockIdx.x & 15) * 64;
  const bf16* src = Vh + (size_t)h * (SEQ*HD);
  bf16* dst = Vt + (size_t)h * (SEQ*HD);
  int tid = threadIdx.x;
  int r  = tid >> 2;
  int c0 = (tid & 3) * 16;
  bf16x8 v0 = *(const bf16x8*)(src + (size_t)(j0 + r)*HD + c0);
  bf16x8 v1 = *(const bf16x8*)(src + (size_t)(j0 + r)*HD + c0 + 8);
  for (int i = 0; i < 8; ++i) { t[r][c0+i] = v0[i]; t[r][c0+8+i] = v1[i]; }
  __syncthreads();
  bf16x8 w0, w1;
  for (int i = 0; i < 8; ++i) { w0[i] = t[c0+i][r]; w1[i] = t[c0+8+i][r]; }
  *(bf16x8*)(dst + (size_t)r*SEQ + j0 + c0)     = w0;
  *(bf16x8*)(dst + (size_t)r*SEQ + j0 + c0 + 8) = w1;
}

// ---------------- fused attention (2-pass, double-buffered) ----------------
// Block = 4 waves x 16 rows = 64 q-rows of one head.
// Pass A: l_i = sum_j exp(S_ij*scale). Pass B: recompute S, write normalized
// fp32 weights (268MB, exactly once), PV accumulate via LDS bf16 roundtrip.
__global__ __launch_bounds__(256) void attn_kernel(const bf16* __restrict__ Qh,
                                                   const bf16* __restrict__ Kh,
                                                   const bf16* __restrict__ Vt,
                                                   float* __restrict__ attn_out,
                                                   bf16* __restrict__ ctx) {
  __shared__ short Ks[2][64*64];     // [j][d] swizzled, double-buffered
  __shared__ short Vs[2][64*64];     // [d][j] swizzled (from Vt)
  __shared__ short Ws[4][16*64];     // per-wave P tile [i][j] swizzled

  const int lane = threadIdx.x & 63;
  const int wid  = threadIdx.x >> 6;
  const int h  = blockIdx.x >> 4;            // b*8+n
  const int i0 = (blockIdx.x & 15) * 64;
  const int b  = h >> 3;
  const int nh = h & 7;

  const bf16* Qhead  = Qh + (size_t)h * (SEQ*HD);
  const bf16* Khead  = Kh + (size_t)h * (SEQ*HD);
  const bf16* Vthead = Vt + (size_t)h * (SEQ*HD);

  const int lrow = lane >> 3;
  const int swz  = ((lane & 7) ^ lrow) * 8;

  const int qrow = i0 + wid*16 + (lane & 15);
  bf16x8 qf[2];
  qf[0] = *(const bf16x8*)(Qhead + (size_t)qrow*HD + (lane>>4)*8);
  qf[1] = *(const bf16x8*)(Qhead + (size_t)qrow*HD + 32 + (lane>>4)*8);

  const f32x4 zero4 = {0.f,0.f,0.f,0.f};

  auto stageK = [&](int buf, int jt) {
    const int j0 = jt * 64;
    for (int i = 0; i < 2; ++i) {
      int c = wid*2 + i;
      gload_lds16(Khead + (size_t)(j0 + c*8 + lrow)*HD + swz, &Ks[buf][c*512]);
    }
  };
  auto stageV = [&](int buf, int jt) {
    const int j0 = jt * 64;
    for (int i = 0; i < 2; ++i) {
      int c = wid*2 + i;
      gload_lds16(Vthead + (size_t)(c*8 + lrow)*SEQ + j0 + swz, &Vs[buf][c*512]);
    }
  };

  // ---- pass A: denominators (K only, double-buffered) ----
  float lsum[4] = {0.f,0.f,0.f,0.f};
  stageK(0, 0);
  asm volatile("s_waitcnt vmcnt(0)" ::: "memory");
  __syncthreads();
  int cur = 0;
  for (int jt = 0; jt < 16; ++jt) {
    if (jt < 15) stageK(cur ^ 1, jt + 1);
    f32x4 sac[4] = {zero4, zero4, zero4, zero4};
    for (int kc = 0; kc < 2; ++kc)
      for (int jf = 0; jf < 4; ++jf) {
        bf16x8 kf = frag_ld(&Ks[cur][0], jf*16 + (lane & 15), (lane>>4) + kc*4);
        sac[jf] = __builtin_amdgcn_mfma_f32_16x16x32_bf16(qf[kc], kf, sac[jf], 0, 0, 0);
      }
    for (int jf = 0; jf < 4; ++jf)
      for (int r = 0; r < 4; ++r)
        lsum[r] += __expf(sac[jf][r] * SCALE_F);
    if (jt < 15) {
      asm volatile("s_waitcnt vmcnt(0)" ::: "memory");
      __syncthreads();
      cur ^= 1;
    }
  }
  for (int m = 1; m < 16; m <<= 1)
    for (int r = 0; r < 4; ++r)
      lsum[r] += __shfl_xor(lsum[r], m, 64);
  float linv[4];
  for (int r = 0; r < 4; ++r) linv[r] = 1.0f / lsum[r];
  __syncthreads();   // all waves done with pass-A tiles before restaging

  // ---- pass B: recompute S, emit normalized weights, PV ----
  f32x4 cacc[4] = {zero4, zero4, zero4, zero4};
  short* Wsw = &Ws[wid][0];
  stageK(0, 0); stageV(0, 0);
  asm volatile("s_waitcnt vmcnt(0)" ::: "memory");
  __syncthreads();
  cur = 0;
  for (int jt = 0; jt < 16; ++jt) {
    if (jt < 15) { stageK(cur ^ 1, jt + 1); stageV(cur ^ 1, jt + 1); }
    const int j0 = jt * 64;
    f32x4 sac[4] = {zero4, zero4, zero4, zero4};
    for (int kc = 0; kc < 2; ++kc)
      for (int jf = 0; jf < 4; ++jf) {
        bf16x8 kf = frag_ld(&Ks[cur][0], jf*16 + (lane & 15), (lane>>4) + kc*4);
        sac[jf] = __builtin_amdgcn_mfma_f32_16x16x32_bf16(qf[kc], kf, sac[jf], 0, 0, 0);
      }
    // normalize, write fp32 attn_weight once, stash bf16 P for PV
    for (int jf = 0; jf < 4; ++jf)
      for (int r = 0; r < 4; ++r) {
        float w = __expf(sac[jf][r] * SCALE_F) * linv[r];
        int row = (lane>>4)*4 + r;
        int col = jf*16 + (lane & 15);
        attn_out[(size_t)(h*SEQ + i0 + wid*16 + row)*SEQ + j0 + col] = w;
        Wsw[row*64 + (((col>>3) ^ (row & 7))<<3) + (col & 7)] = (short)f2bf(w);
      }
    asm volatile("s_waitcnt lgkmcnt(0)" ::: "memory");  // same-wave Ws visibility
    for (int kc = 0; kc < 2; ++kc) {
      bf16x8 wa = frag_ld(Wsw, lane & 15, (lane>>4) + kc*4);
      for (int df = 0; df < 4; ++df) {
        bf16x8 vb = frag_ld(&Vs[cur][0], df*16 + (lane & 15), (lane>>4) + kc*4);
        cacc[df] = __builtin_amdgcn_mfma_f32_16x16x32_bf16(wa, vb, cacc[df], 0, 0, 0);
      }
    }
    if (jt < 15) {
      asm volatile("s_waitcnt vmcnt(0)" ::: "memory");
      __syncthreads();
      cur ^= 1;
    }
  }
  // ctx[b][i'][nh*64+d]  (the transpose(0,2,1,3) happens here)
  for (int df = 0; df < 4; ++df)
    for (int r = 0; r < 4; ++r) {
      int irow = i0 + wid*16 + (lane>>4)*4 + r;
      ((unsigned short*)ctx)[(size_t)(b*SEQ + irow)*WIDTH + nh*HD + df*16 + (lane & 15)]
          = f2bf(cacc[df][r]);
    }
}

// ---------------- launcher ----------------
extern "C" void kernel_launch(void* const* d_in, const int* in_sizes, int n_in,
                              void* d_out, int out_size, void* d_ws, size_t ws_size,
                              hipStream_t stream) {
  const float* q  = (const float*)d_in[0];
  const float* k  = (const float*)d_in[1];
  const float* v  = (const float*)d_in[2];
  const float* wq = (const float*)d_in[3];
  const float* wk = (const float*)d_in[4];
  const float* wv = (const float*)d_in[5];
  const float* wo = (const float*)d_in[6];

  bf16* wsb = (bf16*)d_ws;
  bf16* qb  = wsb;
  bf16* kb  = qb + 4194304;
  bf16* vb  = kb + 4194304;
  bf16* wqb = vb + 4194304;
  bf16* wkb = wqb + 262144;
  bf16* wvb = wkb + 262144;
  bf16* wob = wvb + 262144;
  bf16* Qh  = wob + 262144;
  bf16* Kh  = Qh + 4194304;
  bf16* Vh  = Kh + 4194304;
  bf16* Vt  = Vh + 4194304;
  bf16* ctx = Vt + 4194304;

  float* x_out    = (float*)d_out;             // (8,1024,512)
  float* attn_out = (float*)d_out + 4194304;   // (8,8,1024,1024)

  cast_all_kernel<<<13312, 256, 0, stream>>>(q, k, v, wq, wk, wv, wo, wsb);
  gemm_bt<0,3><<<dim3(64,4,3), 256, 0, stream>>>(qb, kb, vb, wqb, wkb, wvb,
                                                 (void*)Qh, (void*)Kh, (void*)Vh);
  transpose_v<<<1024, 256, 0, stream>>>(Vh, Vt);
  attn_kernel<<<1024, 256, 0, stream>>>(Qh, Kh, Vt, attn_out, ctx);
  gemm_bt<1,1><<<dim3(64,4,1), 256, 0, stream>>>(ctx, nullptr, nullptr, wob, nullptr, nullptr,
                                                 (void*)x_out, nullptr, nullptr);
}

// Round 4
// 144.517 us; speedup vs baseline: 1.5308x; 1.0525x over previous
//
#include <hip/hip_runtime.h>
#include <hip/hip_bf16.h>

// Fused MHA forward (B=8, I=J=1024, WIDTH=512, NH=8, HD=64), fp32 in/out.
// R4: XCD-chunked block swizzles (GEMM: A-panel reuse within XCD; attn: K/V
// head reuse within XCD) + s_setprio around attn MFMA clusters. Structure
// otherwise identical to R3 (2-pass attn, double-buffered staging).

typedef __hip_bfloat16 bf16;
typedef __attribute__((ext_vector_type(8))) short bf16x8;   // MFMA A/B frag (4 VGPR)
typedef __attribute__((ext_vector_type(4))) float f32x4;    // MFMA C/D frag

#define BATCH 8
#define SEQ   1024
#define WIDTH 512
#define NHEAD 8
#define HD    64
#define SCALE_F 0.044194173824159216f     // 512^-0.5 (width, per reference!)

static __device__ __forceinline__ unsigned short f2bf(float x) {
  union { float f; unsigned u; } a; a.f = x;
  unsigned r = a.u + 0x7fffu + ((a.u >> 16) & 1u);   // RNE
  return (unsigned short)(r >> 16);
}

static __device__ __forceinline__ void gload_lds16(const void* g, void* l) {
  __builtin_amdgcn_global_load_lds((const __attribute__((address_space(1))) void*)g,
                                   (__attribute__((address_space(3))) void*)l,
                                   16, 0, 0);
}

// Swizzled LDS tile: rows of 64 bf16 (128B); 16B-unit phys col = logical ^ (row&7).
// Staging pre-applies the inverse on the GLOBAL source; reads apply it here.
static __device__ __forceinline__ bf16x8 frag_ld(const short* tile, int row, int c16) {
  int p = c16 ^ (row & 7);
  return *(const bf16x8*)(tile + row*64 + p*8);
}

// ---------------- cast fp32 -> bf16 (q,k,v + 4 weights) ----------------
__global__ void cast_all_kernel(const float* __restrict__ q, const float* __restrict__ k,
                                const float* __restrict__ v, const float* __restrict__ wq,
                                const float* __restrict__ wk, const float* __restrict__ wv,
                                const float* __restrict__ wo, bf16* __restrict__ wsb) {
  const long NQ = 1048576;   // float4 groups per q/k/v (8192*512/4)
  const long NW = 65536;     // per weight (512*512/4)
  long g = (long)blockIdx.x * blockDim.x + threadIdx.x;
  const float* src; bf16* dst; long o;
  if (g < 3*NQ) {
    int t = (int)(g / NQ); o = g - (long)t*NQ;
    src = (t==0) ? q : ((t==1) ? k : v);
    dst = wsb + (size_t)t * 4194304;
  } else {
    long g2 = g - 3*NQ;
    if (g2 >= 4*NW) return;
    int t = (int)(g2 / NW); o = g2 - (long)t*NW;
    src = (t==0) ? wq : ((t==1) ? wk : ((t==2) ? wv : wo));
    dst = wsb + (size_t)3*4194304 + (size_t)t * 262144;
  }
  float4 f = ((const float4*)src)[o];
  ushort4 r4;
  r4.x = f2bf(f.x); r4.y = f2bf(f.y); r4.z = f2bf(f.z); r4.w = f2bf(f.w);
  ((ushort4*)dst)[o] = r4;
}

// ---------------- GEMM: C[8192][512] = A[8192][512] @ W[512][512]^T ----------------
// 128x128 tile, BK=64, 4 waves (2x2), 2-phase double-buffered staging.
// 1-D grid, XCD-chunked: block b -> xcd=b&7 (HW round-robin), each XCD gets
// complete {m-group x 4 n-panels} sets so A-panels are L2-resident per XCD.
// NZ=3: merged QKV (m-group index g in [0,192) spans z); NZ=1: single GEMM.
template<int F32OUT, int NZ>
__global__ __launch_bounds__(256) void gemm_bt(const bf16* __restrict__ A0, const bf16* __restrict__ A1,
                                               const bf16* __restrict__ A2, const bf16* __restrict__ W0,
                                               const bf16* __restrict__ W1, const bf16* __restrict__ W2,
                                               void* __restrict__ C0, void* __restrict__ C1,
                                               void* __restrict__ C2) {
  __shared__ short As[2][128*64];
  __shared__ short Bs[2][128*64];

  const int bid = blockIdx.x;
  const int xcd = bid & 7;
  const int idx = bid >> 3;                 // [0, 12*NZ*4)
  const int g   = xcd * (8*NZ) + (idx >> 2); // m-group in [0, 64*NZ)
  const int y   = idx & 3;
  const int z   = g >> 6;                   // 0..NZ-1
  const int m   = g & 63;

  const bf16* A; const bf16* Bw; void* Cout;
  if (NZ == 1 || z == 0) { A = A0; Bw = W0; Cout = C0; }
  else if (z == 1)       { A = A1; Bw = W1; Cout = C1; }
  else                   { A = A2; Bw = W2; Cout = C2; }

  const int lane = threadIdx.x & 63;
  const int wid  = threadIdx.x >> 6;
  const int m0 = m * 128;
  const int n0 = y * 128;
  const int wm = (wid >> 1) * 64;
  const int wn = (wid & 1) * 64;
  const int lrow = lane >> 3;
  const int swz  = ((lane & 7) ^ lrow) * 8;

  const f32x4 zero4 = {0.f,0.f,0.f,0.f};
  f32x4 acc[4][4];
  for (int i=0;i<4;++i) for (int j=0;j<4;++j) acc[i][j] = zero4;

  auto stage = [&](int buf, int t) {
    const int k0 = t * 64;
    for (int i = 0; i < 4; ++i) {
      int c = wid*4 + i;
      int row = c*8 + lrow;
      gload_lds16(A  + (size_t)(m0 + row)*WIDTH + k0 + swz, &As[buf][c*512]);
      gload_lds16(Bw + (size_t)(n0 + row)*WIDTH + k0 + swz, &Bs[buf][c*512]);
    }
  };

  stage(0, 0);
  asm volatile("s_waitcnt vmcnt(0)" ::: "memory");
  __syncthreads();
  int cur = 0;

  for (int t = 0; t < 8; ++t) {
    if (t < 7) stage(cur ^ 1, t + 1);
    for (int kc = 0; kc < 2; ++kc) {
      bf16x8 af[4], bfr[4];
      for (int mf=0; mf<4; ++mf) af[mf]  = frag_ld(&As[cur][0], wm + mf*16 + (lane&15), (lane>>4) + kc*4);
      for (int nf=0; nf<4; ++nf) bfr[nf] = frag_ld(&Bs[cur][0], wn + nf*16 + (lane&15), (lane>>4) + kc*4);
      for (int mf=0; mf<4; ++mf)
        for (int nf=0; nf<4; ++nf)
          acc[mf][nf] = __builtin_amdgcn_mfma_f32_16x16x32_bf16(af[mf], bfr[nf], acc[mf][nf], 0,0,0);
    }
    if (t < 7) {
      asm volatile("s_waitcnt vmcnt(0)" ::: "memory");
      __syncthreads();
      cur ^= 1;
    }
  }
  // epilogue: C row = (lane>>4)*4+r, col = lane&15
  for (int mf=0; mf<4; ++mf)
    for (int nf=0; nf<4; ++nf) {
      int col = n0 + wn + nf*16 + (lane & 15);
      for (int r=0; r<4; ++r) {
        int row = m0 + wm + mf*16 + (lane>>4)*4 + r;
        if (F32OUT)
          ((float*)Cout)[(size_t)row*WIDTH + col] = acc[mf][nf][r];
        else
          ((unsigned short*)Cout)[(size_t)row*WIDTH + col] = f2bf(acc[mf][nf][r]);
      }
    }
}

// ---------------- V transpose: per head (1024,64) -> (64,1024) ----------------
__global__ __launch_bounds__(256) void transpose_v(const bf16* __restrict__ Vh,
                                                   bf16* __restrict__ Vt) {
  __shared__ short t[64][72];
  int h  = blockIdx.x >> 4;
  int j0 = (blockIdx.x & 15) * 64;
  const bf16* src = Vh + (size_t)h * (SEQ*HD);
  bf16* dst = Vt + (size_t)h * (SEQ*HD);
  int tid = threadIdx.x;
  int r  = tid >> 2;
  int c0 = (tid & 3) * 16;
  bf16x8 v0 = *(const bf16x8*)(src + (size_t)(j0 + r)*HD + c0);
  bf16x8 v1 = *(const bf16x8*)(src + (size_t)(j0 + r)*HD + c0 + 8);
  for (int i = 0; i < 8; ++i) { t[r][c0+i] = v0[i]; t[r][c0+8+i] = v1[i]; }
  __syncthreads();
  bf16x8 w0, w1;
  for (int i = 0; i < 8; ++i) { w0[i] = t[c0+i][r]; w1[i] = t[c0+8+i][r]; }
  *(bf16x8*)(dst + (size_t)r*SEQ + j0 + c0)     = w0;
  *(bf16x8*)(dst + (size_t)r*SEQ + j0 + c0 + 8) = w1;
}

// ---------------- fused attention (2-pass, double-buffered) ----------------
// Block = 4 waves x 16 rows = 64 q-rows of one head.
// XCD-chunked: each XCD owns 8 whole heads -> K/V (2MB) L2-resident per XCD.
__global__ __launch_bounds__(256) void attn_kernel(const bf16* __restrict__ Qh,
                                                   const bf16* __restrict__ Kh,
                                                   const bf16* __restrict__ Vt,
                                                   float* __restrict__ attn_out,
                                                   bf16* __restrict__ ctx) {
  __shared__ short Ks[2][64*64];     // [j][d] swizzled, double-buffered
  __shared__ short Vs[2][64*64];     // [d][j] swizzled (from Vt)
  __shared__ short Ws[4][16*64];     // per-wave P tile [i][j] swizzled

  const int lane = threadIdx.x & 63;
  const int wid  = threadIdx.x >> 6;
  const int bid  = blockIdx.x;
  const int xcd  = bid & 7;
  const int idx  = bid >> 3;                 // 0..127
  const int h    = xcd*8 + (idx >> 4);       // 8 heads per XCD
  const int i0   = (idx & 15) * 64;
  const int b  = h >> 3;
  const int nh = h & 7;

  const bf16* Qhead  = Qh + (size_t)h * (SEQ*HD);
  const bf16* Khead  = Kh + (size_t)h * (SEQ*HD);
  const bf16* Vthead = Vt + (size_t)h * (SEQ*HD);

  const int lrow = lane >> 3;
  const int swz  = ((lane & 7) ^ lrow) * 8;

  const int qrow = i0 + wid*16 + (lane & 15);
  bf16x8 qf[2];
  qf[0] = *(const bf16x8*)(Qhead + (size_t)qrow*HD + (lane>>4)*8);
  qf[1] = *(const bf16x8*)(Qhead + (size_t)qrow*HD + 32 + (lane>>4)*8);

  const f32x4 zero4 = {0.f,0.f,0.f,0.f};

  auto stageK = [&](int buf, int jt) {
    const int j0 = jt * 64;
    for (int i = 0; i < 2; ++i) {
      int c = wid*2 + i;
      gload_lds16(Khead + (size_t)(j0 + c*8 + lrow)*HD + swz, &Ks[buf][c*512]);
    }
  };
  auto stageV = [&](int buf, int jt) {
    const int j0 = jt * 64;
    for (int i = 0; i < 2; ++i) {
      int c = wid*2 + i;
      gload_lds16(Vthead + (size_t)(c*8 + lrow)*SEQ + j0 + swz, &Vs[buf][c*512]);
    }
  };

  // ---- pass A: denominators (K only, double-buffered) ----
  float lsum[4] = {0.f,0.f,0.f,0.f};
  stageK(0, 0);
  asm volatile("s_waitcnt vmcnt(0)" ::: "memory");
  __syncthreads();
  int cur = 0;
  for (int jt = 0; jt < 16; ++jt) {
    if (jt < 15) stageK(cur ^ 1, jt + 1);
    f32x4 sac[4] = {zero4, zero4, zero4, zero4};
    __builtin_amdgcn_s_setprio(1);
    for (int kc = 0; kc < 2; ++kc)
      for (int jf = 0; jf < 4; ++jf) {
        bf16x8 kf = frag_ld(&Ks[cur][0], jf*16 + (lane & 15), (lane>>4) + kc*4);
        sac[jf] = __builtin_amdgcn_mfma_f32_16x16x32_bf16(qf[kc], kf, sac[jf], 0, 0, 0);
      }
    __builtin_amdgcn_s_setprio(0);
    for (int jf = 0; jf < 4; ++jf)
      for (int r = 0; r < 4; ++r)
        lsum[r] += __expf(sac[jf][r] * SCALE_F);
    if (jt < 15) {
      asm volatile("s_waitcnt vmcnt(0)" ::: "memory");
      __syncthreads();
      cur ^= 1;
    }
  }
  for (int m = 1; m < 16; m <<= 1)
    for (int r = 0; r < 4; ++r)
      lsum[r] += __shfl_xor(lsum[r], m, 64);
  float linv[4];
  for (int r = 0; r < 4; ++r) linv[r] = 1.0f / lsum[r];
  __syncthreads();   // all waves done with pass-A tiles before restaging

  // ---- pass B: recompute S, emit normalized weights, PV ----
  f32x4 cacc[4] = {zero4, zero4, zero4, zero4};
  short* Wsw = &Ws[wid][0];
  stageK(0, 0); stageV(0, 0);
  asm volatile("s_waitcnt vmcnt(0)" ::: "memory");
  __syncthreads();
  cur = 0;
  for (int jt = 0; jt < 16; ++jt) {
    if (jt < 15) { stageK(cur ^ 1, jt + 1); stageV(cur ^ 1, jt + 1); }
    const int j0 = jt * 64;
    f32x4 sac[4] = {zero4, zero4, zero4, zero4};
    __builtin_amdgcn_s_setprio(1);
    for (int kc = 0; kc < 2; ++kc)
      for (int jf = 0; jf < 4; ++jf) {
        bf16x8 kf = frag_ld(&Ks[cur][0], jf*16 + (lane & 15), (lane>>4) + kc*4);
        sac[jf] = __builtin_amdgcn_mfma_f32_16x16x32_bf16(qf[kc], kf, sac[jf], 0, 0, 0);
      }
    __builtin_amdgcn_s_setprio(0);
    // normalize, write fp32 attn_weight once, stash bf16 P for PV
    for (int jf = 0; jf < 4; ++jf)
      for (int r = 0; r < 4; ++r) {
        float w = __expf(sac[jf][r] * SCALE_F) * linv[r];
        int row = (lane>>4)*4 + r;
        int col = jf*16 + (lane & 15);
        attn_out[(size_t)(h*SEQ + i0 + wid*16 + row)*SEQ + j0 + col] = w;
        Wsw[row*64 + (((col>>3) ^ (row & 7))<<3) + (col & 7)] = (short)f2bf(w);
      }
    asm volatile("s_waitcnt lgkmcnt(0)" ::: "memory");  // same-wave Ws visibility
    __builtin_amdgcn_s_setprio(1);
    for (int kc = 0; kc < 2; ++kc) {
      bf16x8 wa = frag_ld(Wsw, lane & 15, (lane>>4) + kc*4);
      for (int df = 0; df < 4; ++df) {
        bf16x8 vb = frag_ld(&Vs[cur][0], df*16 + (lane & 15), (lane>>4) + kc*4);
        cacc[df] = __builtin_amdgcn_mfma_f32_16x16x32_bf16(wa, vb, cacc[df], 0, 0, 0);
      }
    }
    __builtin_amdgcn_s_setprio(0);
    if (jt < 15) {
      asm volatile("s_waitcnt vmcnt(0)" ::: "memory");
      __syncthreads();
      cur ^= 1;
    }
  }
  // ctx[b][i'][nh*64+d]  (the transpose(0,2,1,3) happens here)
  for (int df = 0; df < 4; ++df)
    for (int r = 0; r < 4; ++r) {
      int irow = i0 + wid*16 + (lane>>4)*4 + r;
      ((unsigned short*)ctx)[(size_t)(b*SEQ + irow)*WIDTH + nh*HD + df*16 + (lane & 15)]
          = f2bf(cacc[df][r]);
    }
}

// ---------------- launcher ----------------
extern "C" void kernel_launch(void* const* d_in, const int* in_sizes, int n_in,
                              void* d_out, int out_size, void* d_ws, size_t ws_size,
                              hipStream_t stream) {
  const float* q  = (const float*)d_in[0];
  const float* k  = (const float*)d_in[1];
  const float* v  = (const float*)d_in[2];
  const float* wq = (const float*)d_in[3];
  const float* wk = (const float*)d_in[4];
  const float* wv = (const float*)d_in[5];
  const float* wo = (const float*)d_in[6];

  bf16* wsb = (bf16*)d_ws;
  bf16* qb  = wsb;
  bf16* kb  = qb + 4194304;
  bf16* vb  = kb + 4194304;
  bf16* wqb = vb + 4194304;
  bf16* wkb = wqb + 262144;
  bf16* wvb = wkb + 262144;
  bf16* wob = wvb + 262144;
  bf16* Qh  = wob + 262144;
  bf16* Kh  = Qh + 4194304;
  bf16* Vh  = Kh + 4194304;
  bf16* Vt  = Vh + 4194304;
  bf16* ctx = Vt + 4194304;

  float* x_out    = (float*)d_out;             // (8,1024,512)
  float* attn_out = (float*)d_out + 4194304;   // (8,8,1024,1024)

  cast_all_kernel<<<13312, 256, 0, stream>>>(q, k, v, wq, wk, wv, wo, wsb);
  gemm_bt<0,3><<<768, 256, 0, stream>>>(qb, kb, vb, wqb, wkb, wvb,
                                        (void*)Qh, (void*)Kh, (void*)Vh);
  transpose_v<<<1024, 256, 0, stream>>>(Vh, Vt);
  attn_kernel<<<1024, 256, 0, stream>>>(Qh, Kh, Vt, attn_out, ctx);
  gemm_bt<1,1><<<256, 256, 0, stream>>>(ctx, nullptr, nullptr, wob, nullptr, nullptr,
                                        (void*)x_out, nullptr, nullptr);
}